// Round 6
// baseline (167.476 us; speedup 1.0000x reference)
//
#include <hip/hip_runtime.h>

// FlowNetC correlation, B=8 C=256 H=64 W=128, 9x9 grid.
// out[b,dy*9+dx,h,w] = (1/256) * sum_c in1[b,c,h,w]*in2[b,c,h+dy-4,w+dx-4]
// (in2 zero-padded by 4 in h,w).
//
// Block = (b,h,dy) -> needs ONE in2 row. 4608 blocks x 256 thr (4 waves).
// Thread = (q:16 w-octs) x (cslo:4) ; wave w owns channels 16p+4w+cslo.
// Wave-private staging (no barriers in main loop). Per phase exactly 10 VMEM
// ops (8 global_load_lds + 2 v1 dwordx4) -> uniform FIFO.
// R6: prefetch depth 3 phases (quad-buffered LDS, 4 static v1 reg sets,
// vmcnt(30)) to cover ~900cyc HBM first-touch latency at 3 waves/SIMD.
// R4/R5 lesson: (256,4) budget 128 regs < ~135 working set -> acc spills
// (WRITE 109MB); (256,3)=170 regs -> WRITE == output exactly. Keep (256,3).

#define AS1 __attribute__((address_space(1)))
#define AS3 __attribute__((address_space(3)))

namespace {

constexpr int Cc = 256, Hh = 64, Ww = 128;
constexpr int HW = Hh * Ww;      // 8192
constexpr int ND = 81;
constexpr int ROWF = 136;        // [4 zero|64 even-quads|64 odd-quads|4 zero]
constexpr int WBUF = 4 * ROWF;   // 544 floats: one phase-buffer (4 ch) per wave
constexpr int NBUF = 4;          // quad-buffer -> 3-phase prefetch depth
constexpr int WREG = NBUF * WBUF;  // 2176 floats per wave
constexpr int NPH = 16;          // 16 phases x 16 channels

__device__ __forceinline__ void async4(const float* g, float* l) {
  __builtin_amdgcn_global_load_lds((const AS1 unsigned int*)g,
                                   (AS3 unsigned int*)l, 4, 0, 0);
}

__global__ __launch_bounds__(256, 3) void corr_kernel(
    const float* __restrict__ in1, const float* __restrict__ in2,
    float* __restrict__ out) {
  __shared__ __align__(16) float lds[4 * WREG];  // 8704 f = 34.8 KB (>=4608 reduce)

  const int tid = threadIdx.x;
  const int w = tid >> 6;
  const int lane = tid & 63;
  const int q = lane & 15;
  const int cslo = lane >> 4;

  // XCD swizzle: dispatch i -> XCD i%8; XCD x gets nb in [576x, 576x+576) =
  // batch x. Within an XCD, consecutive nb = same (b,h), 9 dy siblings ->
  // they run concurrently and share the in1 row + overlapping in2 rows in L2.
  const int bid0 = blockIdx.x;
  const int nb = (bid0 & 7) * 576 + (bid0 >> 3);
  const int b = nb / 576;
  const int rem = nb - b * 576;
  const int h = rem / 9;
  const int dy = rem - h * 9;
  const int row2 = h + dy - 4;

  float* outbase = out + (((size_t)b * ND + (size_t)dy * 9) * Hh + h) * Ww;

  if ((unsigned)row2 >= (unsigned)Hh) {  // dy shifts row out of range -> zeros
    if (tid < 144) {
      const int dx = tid >> 4, qq = tid & 15;
      const float4 z = make_float4(0.f, 0.f, 0.f, 0.f);
      *(float4*)(outbase + (size_t)dx * HW + 8 * qq) = z;
      *(float4*)(outbase + (size_t)dx * HW + 8 * qq + 4) = z;
    }
    return;
  }

  const int wb = w * WREG;
  // zero the 8 pad floats of each (buf, ch) row: 4 bufs x 4 ch x 8 = 128/wave
#pragma unroll
  for (int t = 0; t < 2; ++t) {
    const int s = lane + 64 * t;
    const int b2 = s >> 5, rl = s & 31, j = rl >> 3, p = rl & 7;
    lds[wb + b2 * WBUF + j * ROWF + (p < 4 ? p : 128 + p)] = 0.0f;
  }

  // parity-deinterleaved per-lane source x (LDS dest linear; source swizzled
  // so b128 window reads are 16B-aligned, 2-way-free):
  const int xA = 8 * ((lane + 4) >> 2) + ((lane + 4) & 3) - 4;  // -> phys 4+lane
  const int xB = 8 * (lane >> 2) + (lane & 3);                  // -> phys 68+lane
  const float* in2row = in2 + ((size_t)b * Cc * Hh + row2) * Ww;
  const float* v1p =
      in1 + ((size_t)(b * Cc + 4 * w + cslo) * Hh + h) * Ww + 8 * q;

#define STAGE(P, BI)                                                    \
  {                                                                     \
    const float* s0_ = in2row + (size_t)(16 * (P) + 4 * w) * HW;        \
    _Pragma("unroll") for (int j_ = 0; j_ < 4; ++j_) {                  \
      const float* src_ = s0_ + (size_t)j_ * HW;                        \
      async4(src_ + xA, &lds[wb + (BI) * WBUF + j_ * ROWF + 4]);        \
      async4(src_ + xB, &lds[wb + (BI) * WBUF + j_ * ROWF + 68]);       \
    }                                                                   \
  }

#define LOADV1(P, DST)                                                  \
  {                                                                     \
    const float* pp_ = v1p + (size_t)(16 * (P)) * HW;                   \
    const float4 a_ = *(const float4*)pp_;                              \
    const float4 d_ = *(const float4*)(pp_ + 4);                        \
    DST[0] = a_.x; DST[1] = a_.y; DST[2] = a_.z; DST[3] = a_.w;         \
    DST[4] = d_.x; DST[5] = d_.y; DST[6] = d_.z; DST[7] = d_.w;         \
  }

#define COMPUTE(BI, V1)                                                  \
  {                                                                      \
    const int br_ = wb + (BI) * WBUF + cslo * ROWF + 4 * q;              \
    const float4 A_ = *(const float4*)&lds[br_];       /* px 0..3  */    \
    const float4 B_ = *(const float4*)&lds[br_ + 68];  /* px 4..7  */    \
    const float4 C_ = *(const float4*)&lds[br_ + 4];   /* px 8..11 */    \
    const float4 D_ = *(const float4*)&lds[br_ + 72];  /* px 12..15*/    \
    const float t_[16] = {A_.x, A_.y, A_.z, A_.w, B_.x, B_.y, B_.z, B_.w,\
                          C_.x, C_.y, C_.z, C_.w, D_.x, D_.y, D_.z, D_.w};\
    _Pragma("unroll") for (int dx_ = 0; dx_ < 9; ++dx_)                  \
      _Pragma("unroll") for (int px_ = 0; px_ < 8; ++px_)                \
        acc[px_][dx_] = fmaf(V1[px_], t_[px_ + dx_], acc[px_][dx_]);     \
  }

#define VMCNT(N) asm volatile("s_waitcnt vmcnt(" #N ")" ::: "memory")
#define SBAR __builtin_amdgcn_sched_barrier(0)

  float acc[8][9];
#pragma unroll
  for (int px = 0; px < 8; ++px)
#pragma unroll
    for (int dx = 0; dx < 9; ++dx) acc[px][dx] = 0.0f;

  float v1_0[8], v1_1[8], v1_2[8], v1_3[8];
  STAGE(0, 0); LOADV1(0, v1_0);
  STAGE(1, 1); LOADV1(1, v1_1);
  STAGE(2, 2); LOADV1(2, v1_2);

#pragma unroll 1
  for (int pp = 0; pp < 12; pp += 4) {
    STAGE(pp + 3, 3); LOADV1(pp + 3, v1_3);
    VMCNT(30); COMPUTE(0, v1_0); SBAR;
    STAGE(pp + 4, 0); LOADV1(pp + 4, v1_0);
    VMCNT(30); COMPUTE(1, v1_1); SBAR;
    STAGE(pp + 5, 1); LOADV1(pp + 5, v1_1);
    VMCNT(30); COMPUTE(2, v1_2); SBAR;
    STAGE(pp + 6, 2); LOADV1(pp + 6, v1_2);
    VMCNT(30); COMPUTE(3, v1_3); SBAR;
  }
  // tail: phases 12..15 (staging for 12,13,14 already issued; 15 here)
  STAGE(15, 3); LOADV1(15, v1_3);
  VMCNT(30); COMPUTE(0, v1_0); SBAR;  // phase 12
  VMCNT(20); COMPUTE(1, v1_1); SBAR;  // phase 13
  VMCNT(10); COMPUTE(2, v1_2); SBAR;  // phase 14
  VMCNT(0);  COMPUTE(3, v1_3); SBAR;  // phase 15

  // reduce the 4 cslo slices within each wave (lanes q, q+16, q+32, q+48)
#pragma unroll
  for (int px = 0; px < 8; ++px)
#pragma unroll
    for (int dx = 0; dx < 9; ++dx) {
      float v = acc[px][dx];
      v += __shfl_xor(v, 16, 64);
      v += __shfl_xor(v, 32, 64);
      acc[px][dx] = v;
    }

  __syncthreads();  // all waves done with staging region before overwrite
  if (cslo == 0) {  // wave partial: lds[((w*16+q)*9+dx)*8+px]
    const int pb = (w * 16 + q) * 72;
#pragma unroll
    for (int dx = 0; dx < 9; ++dx) {
      *(float4*)&lds[pb + dx * 8] =
          make_float4(acc[0][dx], acc[1][dx], acc[2][dx], acc[3][dx]);
      *(float4*)&lds[pb + dx * 8 + 4] =
          make_float4(acc[4][dx], acc[5][dx], acc[6][dx], acc[7][dx]);
    }
  }
  __syncthreads();

  if (tid < 144) {  // sum 4 wave-partials, scale, store
    const int dx = tid >> 4, qq = tid & 15;
    const float s = 1.0f / 256.0f;
    float r[8];
#pragma unroll
    for (int px = 0; px < 8; ++px) r[px] = 0.0f;
#pragma unroll
    for (int w4 = 0; w4 < 4; ++w4) {
      const int pb = ((w4 * 16 + qq) * 9 + dx) * 8;
      const float4 lo = *(const float4*)&lds[pb];
      const float4 hi = *(const float4*)&lds[pb + 4];
      r[0] += lo.x; r[1] += lo.y; r[2] += lo.z; r[3] += lo.w;
      r[4] += hi.x; r[5] += hi.y; r[6] += hi.z; r[7] += hi.w;
    }
    *(float4*)(outbase + (size_t)dx * HW + 8 * qq) =
        make_float4(r[0] * s, r[1] * s, r[2] * s, r[3] * s);
    *(float4*)(outbase + (size_t)dx * HW + 8 * qq + 4) =
        make_float4(r[4] * s, r[5] * s, r[6] * s, r[7] * s);
  }
}

}  // namespace

extern "C" void kernel_launch(void* const* d_in, const int* in_sizes, int n_in,
                              void* d_out, int out_size, void* d_ws,
                              size_t ws_size, hipStream_t stream) {
  (void)in_sizes; (void)n_in; (void)out_size; (void)d_ws; (void)ws_size;
  const float* in1 = (const float*)d_in[0];
  const float* in2 = (const float*)d_in[1];
  float* outp = (float*)d_out;
  corr_kernel<<<4608, 256, 0, stream>>>(in1, in2, outp);
}

// Round 7
// 130.889 us; speedup vs baseline: 1.2795x; 1.2795x over previous
//
#include <hip/hip_runtime.h>

// FlowNetC correlation, B=8 C=256 H=64 W=128, 9x9 grid.
// out[b,dy*9+dx,h,w] = (1/256) * sum_c in1[b,c,h,w]*in2[b,c,h+dy-4,w+dx-4]
// (in2 zero-padded by 4 in h,w).
//
// Block = (b,h,dy) -> needs ONE in2 row. 4608 blocks x 256 thr (4 waves).
// Thread = (q:16 w-octs) x (cslo:4); wave w owns channels 16p+4w+cslo.
// Wave-private staging, no barriers in main loop; exactly 10 VMEM ops/phase
// (8 global_load_lds + 2 v1 dwordx4) -> uniform FIFO, counted vmcnt.
// R7: depth-2 pipeline via NBUF=3 LDS buffers + 3 v1 reg sets (period-3
// rotation, 3-phase loop body, vmcnt(20)). Minimal delta from R5 (90us,
// zero spill): +1 LDS buffer, +8 regs. R6 lesson: 4-deep/4-wide variant
// spilled (WRITE 388MB) -- allocator, not arithmetic, decides; change one
// axis at a time and watch WRITE_SIZE == 20736 KB as the spill tripwire.
// R4/R5 lesson: keep __launch_bounds__(256,3); (256,4)'s 128-reg budget spills.

#define AS1 __attribute__((address_space(1)))
#define AS3 __attribute__((address_space(3)))

namespace {

constexpr int Cc = 256, Hh = 64, Ww = 128;
constexpr int HW = Hh * Ww;      // 8192
constexpr int ND = 81;
constexpr int ROWF = 136;        // [4 zero|64 even-quads|64 odd-quads|4 zero]
constexpr int WBUF = 4 * ROWF;   // 544 floats: one phase-buffer (4 ch) per wave
constexpr int NBUF = 3;          // triple-buffer -> staging 2 phases ahead
constexpr int WREG = NBUF * WBUF;  // 1632 floats per wave

__device__ __forceinline__ void async4(const float* g, float* l) {
  __builtin_amdgcn_global_load_lds((const AS1 unsigned int*)g,
                                   (AS3 unsigned int*)l, 4, 0, 0);
}

__global__ __launch_bounds__(256, 3) void corr_kernel(
    const float* __restrict__ in1, const float* __restrict__ in2,
    float* __restrict__ out) {
  __shared__ __align__(16) float lds[4 * WREG];  // 6528 f = 26.1 KB (>4608 reduce)

  const int tid = threadIdx.x;
  const int w = tid >> 6;
  const int lane = tid & 63;
  const int q = lane & 15;
  const int cslo = lane >> 4;

  // XCD swizzle: dispatch i -> XCD i%8; XCD x gets nb in [576x,576x+576) =
  // batch x; 9 dy-siblings of one (b,h) are consecutive -> co-resident,
  // sharing the in1 row and overlapping in2 rows in that XCD's L2.
  const int bid0 = blockIdx.x;
  const int nb = (bid0 & 7) * 576 + (bid0 >> 3);
  const int b = nb / 576;
  const int rem = nb - b * 576;
  const int h = rem / 9;
  const int dy = rem - h * 9;
  const int row2 = h + dy - 4;

  float* outbase = out + (((size_t)b * ND + (size_t)dy * 9) * Hh + h) * Ww;

  if ((unsigned)row2 >= (unsigned)Hh) {  // dy shifts row out of range -> zeros
    if (tid < 144) {
      const int dx = tid >> 4, qq = tid & 15;
      const float4 z = make_float4(0.f, 0.f, 0.f, 0.f);
      *(float4*)(outbase + (size_t)dx * HW + 8 * qq) = z;
      *(float4*)(outbase + (size_t)dx * HW + 8 * qq + 4) = z;
    }
    return;
  }

  const int wb = w * WREG;
  // zero the 8 pad floats of each (buf, ch) row: 3 bufs x 4 ch x 8 = 96/wave
  for (int s = lane; s < 96; s += 64) {
    const int b2 = s >> 5, rl = s & 31, j = rl >> 3, p = rl & 7;
    lds[wb + b2 * WBUF + j * ROWF + (p < 4 ? p : 128 + p)] = 0.0f;
  }

  // parity-deinterleaved per-lane source x (LDS dest linear; source swizzled
  // so b128 window reads are 16B-aligned, 2-way-free):
  const int xA = 8 * ((lane + 4) >> 2) + ((lane + 4) & 3) - 4;  // -> phys 4+lane
  const int xB = 8 * (lane >> 2) + (lane & 3);                  // -> phys 68+lane
  const float* in2row = in2 + ((size_t)b * Cc * Hh + row2) * Ww;
  const float* v1p =
      in1 + ((size_t)(b * Cc + 4 * w + cslo) * Hh + h) * Ww + 8 * q;

#define STAGE(P, BI)                                                    \
  {                                                                     \
    const float* s0_ = in2row + (size_t)(16 * (P) + 4 * w) * HW;        \
    _Pragma("unroll") for (int j_ = 0; j_ < 4; ++j_) {                  \
      const float* src_ = s0_ + (size_t)j_ * HW;                        \
      async4(src_ + xA, &lds[wb + (BI) * WBUF + j_ * ROWF + 4]);        \
      async4(src_ + xB, &lds[wb + (BI) * WBUF + j_ * ROWF + 68]);       \
    }                                                                   \
  }

#define LOADV1(P, DST)                                                  \
  {                                                                     \
    const float* pp_ = v1p + (size_t)(16 * (P)) * HW;                   \
    const float4 a_ = *(const float4*)pp_;                              \
    const float4 d_ = *(const float4*)(pp_ + 4);                        \
    DST[0] = a_.x; DST[1] = a_.y; DST[2] = a_.z; DST[3] = a_.w;         \
    DST[4] = d_.x; DST[5] = d_.y; DST[6] = d_.z; DST[7] = d_.w;         \
  }

#define COMPUTE(BI, V1)                                                  \
  {                                                                      \
    const int br_ = wb + (BI) * WBUF + cslo * ROWF + 4 * q;              \
    const float4 A_ = *(const float4*)&lds[br_];       /* px 0..3  */    \
    const float4 B_ = *(const float4*)&lds[br_ + 68];  /* px 4..7  */    \
    const float4 C_ = *(const float4*)&lds[br_ + 4];   /* px 8..11 */    \
    const float4 D_ = *(const float4*)&lds[br_ + 72];  /* px 12..15*/    \
    const float t_[16] = {A_.x, A_.y, A_.z, A_.w, B_.x, B_.y, B_.z, B_.w,\
                          C_.x, C_.y, C_.z, C_.w, D_.x, D_.y, D_.z, D_.w};\
    _Pragma("unroll") for (int dx_ = 0; dx_ < 9; ++dx_)                  \
      _Pragma("unroll") for (int px_ = 0; px_ < 8; ++px_)                \
        acc[px_][dx_] = fmaf(V1[px_], t_[px_ + dx_], acc[px_][dx_]);     \
  }

#define VMCNT(N) asm volatile("s_waitcnt vmcnt(" #N ")" ::: "memory")
#define SBAR __builtin_amdgcn_sched_barrier(0)

  float acc[8][9];
#pragma unroll
  for (int px = 0; px < 8; ++px)
#pragma unroll
    for (int dx = 0; dx < 9; ++dx) acc[px][dx] = 0.0f;

  float v1_0[8], v1_1[8], v1_2[8];
  STAGE(0, 0); LOADV1(0, v1_0);
  STAGE(1, 1); LOADV1(1, v1_1);

  // phase p: issue stage/v1 for p+2, drain p (vmcnt(20) = keep p+1,p+2's
  // 20 ops in flight), compute p. Buffer/set = p%3. 4 iters x 3 phases.
#pragma unroll 1
  for (int pp = 0; pp < 12; pp += 3) {
    STAGE(pp + 2, 2); LOADV1(pp + 2, v1_2);
    VMCNT(20); COMPUTE(0, v1_0); SBAR;
    STAGE(pp + 3, 0); LOADV1(pp + 3, v1_0);
    VMCNT(20); COMPUTE(1, v1_1); SBAR;
    STAGE(pp + 4, 1); LOADV1(pp + 4, v1_1);
    VMCNT(20); COMPUTE(2, v1_2); SBAR;
  }
  // phases 12..15 (staging for 12,13 already issued)
  STAGE(14, 2); LOADV1(14, v1_2);
  VMCNT(20); COMPUTE(0, v1_0); SBAR;   // phase 12
  STAGE(15, 0); LOADV1(15, v1_0);
  VMCNT(20); COMPUTE(1, v1_1); SBAR;   // phase 13
  VMCNT(10); COMPUTE(2, v1_2); SBAR;   // phase 14
  VMCNT(0);  COMPUTE(0, v1_0); SBAR;   // phase 15

  // reduce the 4 cslo slices within each wave (lanes q, q+16, q+32, q+48)
#pragma unroll
  for (int px = 0; px < 8; ++px)
#pragma unroll
    for (int dx = 0; dx < 9; ++dx) {
      float v = acc[px][dx];
      v += __shfl_xor(v, 16, 64);
      v += __shfl_xor(v, 32, 64);
      acc[px][dx] = v;
    }

  __syncthreads();  // all waves done with staging region before overwrite
  if (cslo == 0) {  // wave partial: lds[((w*16+q)*9+dx)*8+px]
    const int pb = (w * 16 + q) * 72;
#pragma unroll
    for (int dx = 0; dx < 9; ++dx) {
      *(float4*)&lds[pb + dx * 8] =
          make_float4(acc[0][dx], acc[1][dx], acc[2][dx], acc[3][dx]);
      *(float4*)&lds[pb + dx * 8 + 4] =
          make_float4(acc[4][dx], acc[5][dx], acc[6][dx], acc[7][dx]);
    }
  }
  __syncthreads();

  if (tid < 144) {  // sum 4 wave-partials, scale, store
    const int dx = tid >> 4, qq = tid & 15;
    const float s = 1.0f / 256.0f;
    float r[8];
#pragma unroll
    for (int px = 0; px < 8; ++px) r[px] = 0.0f;
#pragma unroll
    for (int w4 = 0; w4 < 4; ++w4) {
      const int pb = ((w4 * 16 + qq) * 9 + dx) * 8;
      const float4 lo = *(const float4*)&lds[pb];
      const float4 hi = *(const float4*)&lds[pb + 4];
      r[0] += lo.x; r[1] += lo.y; r[2] += lo.z; r[3] += lo.w;
      r[4] += hi.x; r[5] += hi.y; r[6] += hi.z; r[7] += hi.w;
    }
    *(float4*)(outbase + (size_t)dx * HW + 8 * qq) =
        make_float4(r[0] * s, r[1] * s, r[2] * s, r[3] * s);
    *(float4*)(outbase + (size_t)dx * HW + 8 * qq + 4) =
        make_float4(r[4] * s, r[5] * s, r[6] * s, r[7] * s);
  }
}

}  // namespace

extern "C" void kernel_launch(void* const* d_in, const int* in_sizes, int n_in,
                              void* d_out, int out_size, void* d_ws,
                              size_t ws_size, hipStream_t stream) {
  (void)in_sizes; (void)n_in; (void)out_size; (void)d_ws; (void)ws_size;
  const float* in1 = (const float*)d_in[0];
  const float* in2 = (const float*)d_in[1];
  float* outp = (float*)d_out;
  corr_kernel<<<4608, 256, 0, stream>>>(in1, in2, outp);
}

// Round 8
// 87.320 us; speedup vs baseline: 1.9180x; 1.4990x over previous
//
#include <hip/hip_runtime.h>

// FlowNetC correlation, B=8 C=256 H=64 W=128, 9x9 grid.
// out[b,dy*9+dx,h,w] = (1/256) * sum_c in1[b,c,h,w]*in2[b,c,h+dy-4,w+dx-4]
// (in2 zero-padded by 4 in h,w).
//
// Block = (b,h,dy) -> needs ONE in2 row. 4608 blocks x 256 thr (4 waves).
// Thread = (q:16 w-octs) x (cslo:4); wave w owns channels 16p+4w+cslo.
// Wave-private staging, no barriers in main loop; counted vmcnt.
// R8 (single change vs R5-90us): staging width 4 -> 16. Per phase: TWO
// global_load_lds dwordx4 (1 KB each = 2 channel-rows) + 2 v1 dwordx4 =
// 4 VMEM ops (was 10). Theory: width-4 LDS-DMA cost is per-instruction
// (~8 serialized ops ~= the observed ~2000cyc/phase drain; guide m193:
// width 4->16 alone +67%).
// Layout: per channel 32 quads as [odds|evens] rotated by 2*cslo slots
// (bank-uniform reads, replaces the old 136-stride pad layout); window
// edges (q=0 t0..3, q=15 t12..15) read a per-buffer zero slot via
// PRECOMPUTED per-thread read offsets -> zero inner-loop cost.
// R4-R7 lessons: (256,3) only spill-free point; any extra reg-pipeline
// depth spills (WRITE_SIZE tripwire: must be exactly 20736 KB).

#define AS1 __attribute__((address_space(1)))
#define AS3 __attribute__((address_space(3)))

namespace {

constexpr int Cc = 256, Hh = 64, Ww = 128;
constexpr int HW = Hh * Ww;   // 8192
constexpr int ND = 81;
constexpr int PBUF = 520;     // floats per phase buffer: 512 data + 4 zero + pad
constexpr int WREG = 2 * PBUF;  // 1040 floats per wave (double-buffered)

__device__ __forceinline__ void async16(const float* g, float* l) {
  __builtin_amdgcn_global_load_lds((const AS1 unsigned int*)g,
                                   (AS3 unsigned int*)l, 16, 0, 0);
}

__global__ __launch_bounds__(256, 3) void corr_kernel(
    const float* __restrict__ in1, const float* __restrict__ in2,
    float* __restrict__ out) {
  __shared__ __align__(16) float lds[4608];  // staging 4x1040=4160; reduce 4608

  const int tid = threadIdx.x;
  const int w = tid >> 6;
  const int lane = tid & 63;
  const int q = lane & 15;
  const int cslo = lane >> 4;

  // XCD swizzle: dispatch i -> XCD i%8; XCD x gets batch x; 9 dy-siblings of
  // one (b,h) are consecutive -> co-resident, sharing rows in that XCD's L2.
  const int bid0 = blockIdx.x;
  const int nb = (bid0 & 7) * 576 + (bid0 >> 3);
  const int b = nb / 576;
  const int rem = nb - b * 576;
  const int h = rem / 9;
  const int dy = rem - h * 9;
  const int row2 = h + dy - 4;

  float* outbase = out + (((size_t)b * ND + (size_t)dy * 9) * Hh + h) * Ww;

  if ((unsigned)row2 >= (unsigned)Hh) {  // dy shifts row out of range -> zeros
    if (tid < 144) {
      const int dx = tid >> 4, qq = tid & 15;
      const float4 z = make_float4(0.f, 0.f, 0.f, 0.f);
      *(float4*)(outbase + (size_t)dx * HW + 8 * qq) = z;
      *(float4*)(outbase + (size_t)dx * HW + 8 * qq + 4) = z;
    }
    return;
  }

  const int wb = w * WREG;
  // zero the 16-B zero-slot of each phase buffer (floats 512..515)
  if (lane < 8) lds[wb + (lane >> 2) * PBUF + 512 + (lane & 3)] = 0.0f;

  // ---- staging source mapping (inverse of the LDS layout) ----
  // dest slot s (16B units) in [0,128): c = s>>5 (local channel), v = s&31,
  // vp = (v - 2c) & 31 ; quad g = vp<16 ? 2*vp+1 : 2*(vp-16)  [odds|evens]
  // instr k covers slots 64k + lane.
  int srcA, srcB;
  {
    const int s0 = lane, c0 = s0 >> 5, v0 = s0 & 31;
    const int vp0 = (v0 - 2 * c0) & 31;
    const int g0 = (vp0 < 16) ? (2 * vp0 + 1) : (2 * (vp0 - 16));
    srcA = (4 * w + c0) * HW + 4 * g0;
    const int s1 = 64 + lane, c1 = s1 >> 5, v1_ = s1 & 31;
    const int vp1 = (v1_ - 2 * c1) & 31;
    const int g1 = (vp1 < 16) ? (2 * vp1 + 1) : (2 * (vp1 - 16));
    srcB = (4 * w + c1) * HW + 4 * g1;
  }

  // ---- per-thread window read offsets (floats, within phase buffer) ----
  // window t[k] = x 8q-4+k ; quads 2q-1, 2q, 2q+1, 2q+2 at layout positions
  // P = {q-1, 16+q, q, 17+q}, slot = cslo*32 + ((P + 2*cslo)&31).
  // q==0 first / q==15 last quad -> zero slot (float 512).
  const int ro0 = (q == 0) ? 512 : (cslo * 32 + ((q - 1 + 2 * cslo) & 31)) * 4;
  const int ro1 = (cslo * 32 + ((16 + q + 2 * cslo) & 31)) * 4;
  const int ro2 = (cslo * 32 + ((q + 2 * cslo) & 31)) * 4;
  const int ro3 = (q == 15) ? 512 : (cslo * 32 + ((17 + q + 2 * cslo) & 31)) * 4;

  const float* in2row = in2 + ((size_t)b * Cc * Hh + row2) * Ww;
  const float* v1p =
      in1 + ((size_t)(b * Cc + 4 * w + cslo) * Hh + h) * Ww + 8 * q;

#define STAGE(P, BI)                                                   \
  {                                                                    \
    const float* s0_ = in2row + (size_t)(16 * (P)) * HW;               \
    async16(s0_ + srcA, &lds[wb + (BI) * PBUF]);                       \
    async16(s0_ + srcB, &lds[wb + (BI) * PBUF + 256]);                 \
  }

#define LOADV1(P, DST)                                                 \
  {                                                                    \
    const float* pp_ = v1p + (size_t)(16 * (P)) * HW;                  \
    const float4 a_ = *(const float4*)pp_;                             \
    const float4 d_ = *(const float4*)(pp_ + 4);                       \
    DST[0] = a_.x; DST[1] = a_.y; DST[2] = a_.z; DST[3] = a_.w;        \
    DST[4] = d_.x; DST[5] = d_.y; DST[6] = d_.z; DST[7] = d_.w;        \
  }

#define COMPUTE(BI, V1)                                                  \
  {                                                                      \
    const int bb_ = wb + (BI) * PBUF;                                    \
    const float4 A_ = *(const float4*)&lds[bb_ + ro0]; /* t0..3  */      \
    const float4 B_ = *(const float4*)&lds[bb_ + ro1]; /* t4..7  */      \
    const float4 C_ = *(const float4*)&lds[bb_ + ro2]; /* t8..11 */      \
    const float4 D_ = *(const float4*)&lds[bb_ + ro3]; /* t12..15*/      \
    const float t_[16] = {A_.x, A_.y, A_.z, A_.w, B_.x, B_.y, B_.z, B_.w,\
                          C_.x, C_.y, C_.z, C_.w, D_.x, D_.y, D_.z, D_.w};\
    _Pragma("unroll") for (int dx_ = 0; dx_ < 9; ++dx_)                  \
      _Pragma("unroll") for (int px_ = 0; px_ < 8; ++px_)                \
        acc[px_][dx_] = fmaf(V1[px_], t_[px_ + dx_], acc[px_][dx_]);     \
  }

#define VMCNT(N) asm volatile("s_waitcnt vmcnt(" #N ")" ::: "memory")

  float acc[8][9];
#pragma unroll
  for (int px = 0; px < 8; ++px)
#pragma unroll
    for (int dx = 0; dx < 9; ++dx) acc[px][dx] = 0.0f;

  float v1a[8], v1b[8];
  STAGE(0, 0); LOADV1(0, v1a);

#pragma unroll 1
  for (int pp = 0; pp < 16; pp += 2) {
    STAGE(pp + 1, 1); LOADV1(pp + 1, v1b);
    VMCNT(4);  // drain phase pp; keep pp+1's 4 ops in flight
    COMPUTE(0, v1a);
    if (pp + 2 < 16) {
      STAGE(pp + 2, 0); LOADV1(pp + 2, v1a);
      VMCNT(4);
    } else {
      VMCNT(0);
    }
    COMPUTE(1, v1b);
  }

  // reduce the 4 cslo slices within each wave (lanes q, q+16, q+32, q+48)
#pragma unroll
  for (int px = 0; px < 8; ++px)
#pragma unroll
    for (int dx = 0; dx < 9; ++dx) {
      float v = acc[px][dx];
      v += __shfl_xor(v, 16, 64);
      v += __shfl_xor(v, 32, 64);
      acc[px][dx] = v;
    }

  __syncthreads();  // all waves done with staging region before overwrite
  if (cslo == 0) {  // wave partial: lds[((w*16+q)*9+dx)*8+px]
    const int pb = (w * 16 + q) * 72;
#pragma unroll
    for (int dx = 0; dx < 9; ++dx) {
      *(float4*)&lds[pb + dx * 8] =
          make_float4(acc[0][dx], acc[1][dx], acc[2][dx], acc[3][dx]);
      *(float4*)&lds[pb + dx * 8 + 4] =
          make_float4(acc[4][dx], acc[5][dx], acc[6][dx], acc[7][dx]);
    }
  }
  __syncthreads();

  if (tid < 144) {  // sum 4 wave-partials, scale, store
    const int dx = tid >> 4, qq = tid & 15;
    const float s = 1.0f / 256.0f;
    float r[8];
#pragma unroll
    for (int px = 0; px < 8; ++px) r[px] = 0.0f;
#pragma unroll
    for (int w4 = 0; w4 < 4; ++w4) {
      const int pb = ((w4 * 16 + qq) * 9 + dx) * 8;
      const float4 lo = *(const float4*)&lds[pb];
      const float4 hi = *(const float4*)&lds[pb + 4];
      r[0] += lo.x; r[1] += lo.y; r[2] += lo.z; r[3] += lo.w;
      r[4] += hi.x; r[5] += hi.y; r[6] += hi.z; r[7] += hi.w;
    }
    *(float4*)(outbase + (size_t)dx * HW + 8 * qq) =
        make_float4(r[0] * s, r[1] * s, r[2] * s, r[3] * s);
    *(float4*)(outbase + (size_t)dx * HW + 8 * qq + 4) =
        make_float4(r[4] * s, r[5] * s, r[6] * s, r[7] * s);
  }
}

}  // namespace

extern "C" void kernel_launch(void* const* d_in, const int* in_sizes, int n_in,
                              void* d_out, int out_size, void* d_ws,
                              size_t ws_size, hipStream_t stream) {
  (void)in_sizes; (void)n_in; (void)out_size; (void)d_ws; (void)ws_size;
  const float* in1 = (const float*)d_in[0];
  const float* in2 = (const float*)d_in[1];
  float* outp = (float*)d_out;
  corr_kernel<<<4608, 256, 0, stream>>>(in1, in2, outp);
}